// Round 1
// baseline (1527.412 us; speedup 1.0000x reference)
//
#include <hip/hip_runtime.h>

// Graphormer encoder, fp32 correctness-first implementation.
// Structure exploit: attention is block-diagonal (64 graphs x 32 nodes).

#define NG   64      // graphs
#define NP   31      // orig nodes per graph
#define NORI 1984    // original nodes
#define NT   2048    // total nodes
#define DIM  512
#define NHD  8
#define DKH  64
#define FFD  2048
#define NLAY 4
#define NFEA 32

// ---------------------------------------------------------------- build B blocks
__global__ __launch_bounds__(256) void build_B(
    const int* __restrict__ sp, const float* __restrict__ db,
    const float* __restrict__ virt_bias, float* __restrict__ Bg)
{
    int g = blockIdx.x;
    float vb = virt_bias[0];
    for (int e = threadIdx.x; e < 1024; e += 256) {
        int i = e >> 5, j = e & 31;
        float v;
        if (i == j) {
            v = db[0];
        } else if (i < NP && j < NP) {
            int s = sp[(size_t)(g * NP + i) * NORI + g * NP + j];
            v = db[s < 100 ? s : 100];
        } else {
            v = vb;
        }
        Bg[(size_t)g * 1024 + e] = v;
    }
}

// ---------------------------------------------------------------- init h
__global__ __launch_bounds__(256) void init_h(
    const float* __restrict__ x, const int* __restrict__ degrees,
    const float* __restrict__ init_W, const float* __restrict__ init_b,
    const float* __restrict__ cent_emb, float* __restrict__ h)
{
    int n = blockIdx.x;
    int tid = threadIdx.x;
    __shared__ float xs[NFEA];
    if (n < NORI && tid < NFEA) xs[tid] = x[(size_t)n * NFEA + tid];
    __syncthreads();
    int deg = degrees[n]; if (deg > 100) deg = 100;
    for (int d = tid; d < DIM; d += 256) {
        float v = cent_emb[(size_t)deg * DIM + d];
        if (n < NORI) {
            float acc = init_b[d];
            #pragma unroll
            for (int k = 0; k < NFEA; ++k) acc += xs[k] * init_W[(size_t)k * DIM + d];
            v += acc;
        }
        h[(size_t)n * DIM + d] = v;
    }
}

// ---------------------------------------------------------------- rearrange QKV weights
// Wq/Wk/Wv[l]: [H, D, DK] -> Wqkv[l]: [D, 1536] with cols 0..511=Q(head-major),
// 512..1023=K, 1024..1535=V. Also builds combined bias [l][1536].
__global__ __launch_bounds__(256) void rearrange_qkv(
    const float* __restrict__ Wq, const float* __restrict__ Wk, const float* __restrict__ Wv,
    const float* __restrict__ bq, const float* __restrict__ bk, const float* __restrict__ bv,
    float* __restrict__ Wqkv, float* __restrict__ bqkv)
{
    int idx = blockIdx.x * 256 + threadIdx.x;
    int total = NLAY * DIM * 1536;
    if (idx < total) {
        int l = idx / (DIM * 1536);
        int rem = idx % (DIM * 1536);
        int d = rem / 1536;
        int c = rem % 1536;
        int which = c >> 9;
        int cc = c & 511;
        int hh = cc >> 6, k = cc & 63;
        const float* W = (which == 0) ? Wq : (which == 1) ? Wk : Wv;
        Wqkv[idx] = W[(((size_t)l * NHD + hh) * DIM + d) * DKH + k];
    }
    if (idx < NLAY * 1536) {
        int l = idx / 1536, c = idx % 1536;
        int which = c >> 9, cc = c & 511;
        const float* b = (which == 0) ? bq : (which == 1) ? bk : bv;
        bqkv[idx] = b[(size_t)l * 512 + cc];
    }
}

// ---------------------------------------------------------------- layernorm (no affine)
__global__ __launch_bounds__(256) void layernorm(
    const float* __restrict__ in, float* __restrict__ out)
{
    int n = blockIdx.x;
    int tid = threadIdx.x;
    const float* row = in + (size_t)n * DIM;
    float v0 = row[tid], v1 = row[tid + 256];
    float s = v0 + v1;
    float sq = v0 * v0 + v1 * v1;
    #pragma unroll
    for (int off = 32; off > 0; off >>= 1) {
        s  += __shfl_down(s, off);
        sq += __shfl_down(sq, off);
    }
    __shared__ float red[8];
    int wave = tid >> 6;
    if ((tid & 63) == 0) { red[wave] = s; red[4 + wave] = sq; }
    __syncthreads();
    float ts  = red[0] + red[1] + red[2] + red[3];
    float tsq = red[4] + red[5] + red[6] + red[7];
    float m   = ts * (1.0f / DIM);
    float var = tsq * (1.0f / DIM) - m * m;
    float inv = rsqrtf(var + 1e-5f);
    out[(size_t)n * DIM + tid]       = (v0 - m) * inv;
    out[(size_t)n * DIM + tid + 256] = (v1 - m) * inv;
}

// ---------------------------------------------------------------- fp32 tiled GEMM
// C[M,N] = op(A[M,K] @ B[K,N] + bias) (+ resid). 64x64x16 tile, 256 thr, 4x4/thr.
__global__ __launch_bounds__(256) void gemm_f32(
    const float* __restrict__ A, const float* __restrict__ B,
    const float* __restrict__ bias, const float* __restrict__ resid,
    float* __restrict__ C, int M, int N, int K, int do_relu)
{
    __shared__ float As[16][68];
    __shared__ float Bs[16][68];
    int tid = threadIdx.x;
    int row0 = blockIdx.y * 64, col0 = blockIdx.x * 64;
    int tx = tid & 15, ty = tid >> 4;
    int am = tid >> 2, ak = (tid & 3) * 4;
    int bk_ = tid >> 4, bn_ = (tid & 15) * 4;
    float acc[4][4] = {};
    for (int k0 = 0; k0 < K; k0 += 16) {
        float4 a4 = *(const float4*)(A + (size_t)(row0 + am) * K + k0 + ak);
        As[ak + 0][am] = a4.x; As[ak + 1][am] = a4.y;
        As[ak + 2][am] = a4.z; As[ak + 3][am] = a4.w;
        float4 b4 = *(const float4*)(B + (size_t)(k0 + bk_) * N + col0 + bn_);
        *(float4*)&Bs[bk_][bn_] = b4;
        __syncthreads();
        #pragma unroll
        for (int kk = 0; kk < 16; ++kk) {
            float4 av = *(const float4*)&As[kk][ty * 4];
            float4 bv = *(const float4*)&Bs[kk][tx * 4];
            float ar[4] = {av.x, av.y, av.z, av.w};
            float br[4] = {bv.x, bv.y, bv.z, bv.w};
            #pragma unroll
            for (int i = 0; i < 4; ++i)
                #pragma unroll
                for (int j = 0; j < 4; ++j)
                    acc[i][j] += ar[i] * br[j];
        }
        __syncthreads();
    }
    #pragma unroll
    for (int i = 0; i < 4; ++i) {
        int r = row0 + ty * 4 + i;
        #pragma unroll
        for (int j = 0; j < 4; ++j) {
            int c = col0 + tx * 4 + j;
            float v = acc[i][j];
            if (bias) v += bias[c];
            if (do_relu) v = fmaxf(v, 0.0f);
            if (resid) v += resid[(size_t)r * N + c];
            C[(size_t)r * N + c] = v;
        }
    }
}

// ---------------------------------------------------------------- block attention
// One block per (graph, head): 32x32 scores + softmax + PV.
__global__ __launch_bounds__(256) void attention(
    const float* __restrict__ qkv,  // [NT][1536], Q|K|V head-major
    const float* __restrict__ Bg,   // [NG][32][32]
    float* __restrict__ O)          // [NT][512] head-major
{
    int g = blockIdx.x >> 3;
    int hh = blockIdx.x & 7;
    __shared__ float Qs[32][64], Ks[32][64], Vs[32][64];
    __shared__ float S[32][32];
    int tid = threadIdx.x;
    int i = tid >> 3;
    int c0 = (tid & 7) * 8;
    int gn = (i < NP) ? g * NP + i : NORI + g;
    const float* base = qkv + (size_t)gn * 1536 + hh * DKH;
    *(float4*)&Qs[i][c0]     = *(const float4*)(base + c0);
    *(float4*)&Qs[i][c0 + 4] = *(const float4*)(base + c0 + 4);
    *(float4*)&Ks[i][c0]     = *(const float4*)(base + 512 + c0);
    *(float4*)&Ks[i][c0 + 4] = *(const float4*)(base + 512 + c0 + 4);
    *(float4*)&Vs[i][c0]     = *(const float4*)(base + 1024 + c0);
    *(float4*)&Vs[i][c0 + 4] = *(const float4*)(base + 1024 + c0 + 4);
    __syncthreads();
    const float scale = 0.125f;  // 1/sqrt(64)
    #pragma unroll
    for (int e = 0; e < 4; ++e) {
        int idx = tid + e * 256;
        int si = idx >> 5, sj = idx & 31;
        float dot = 0.0f;
        #pragma unroll
        for (int k = 0; k < DKH; ++k) dot += Qs[si][k] * Ks[sj][k];
        S[si][sj] = dot * scale + Bg[(size_t)g * 1024 + si * 32 + sj];
    }
    __syncthreads();
    if (tid < 32) {
        float mx = -1e30f;
        #pragma unroll
        for (int j = 0; j < 32; ++j) mx = fmaxf(mx, S[tid][j]);
        float sum = 0.0f;
        #pragma unroll
        for (int j = 0; j < 32; ++j) { float e = __expf(S[tid][j] - mx); S[tid][j] = e; sum += e; }
        float inv = 1.0f / sum;
        #pragma unroll
        for (int j = 0; j < 32; ++j) S[tid][j] *= inv;
    }
    __syncthreads();
    float out[8];
    #pragma unroll
    for (int cc = 0; cc < 8; ++cc) {
        float acc = 0.0f;
        #pragma unroll
        for (int j = 0; j < 32; ++j) acc += S[i][j] * Vs[j][c0 + cc];
        out[cc] = acc;
    }
    float* op = O + (size_t)gn * DIM + hh * DKH + c0;
    *(float4*)op       = make_float4(out[0], out[1], out[2], out[3]);
    *(float4*)(op + 4) = make_float4(out[4], out[5], out[6], out[7]);
}

// ---------------------------------------------------------------- launch
extern "C" void kernel_launch(void* const* d_in, const int* in_sizes, int n_in,
                              void* d_out, int out_size, void* d_ws, size_t ws_size,
                              hipStream_t stream)
{
    const float* x        = (const float*)d_in[0];
    const int*   sp       = (const int*)d_in[1];
    // d_in[2] batch_ids: structure known (31 per graph + trailing virtuals)
    const int*   degrees  = (const int*)d_in[3];
    const float* init_W   = (const float*)d_in[4];
    const float* init_b   = (const float*)d_in[5];
    const float* cent_emb = (const float*)d_in[6];
    const float* db       = (const float*)d_in[7];
    const float* vbias    = (const float*)d_in[8];
    const float* Wq       = (const float*)d_in[9];
    const float* bq       = (const float*)d_in[10];
    const float* Wk       = (const float*)d_in[11];
    const float* bk       = (const float*)d_in[12];
    const float* Wv       = (const float*)d_in[13];
    const float* bv       = (const float*)d_in[14];
    const float* Wo       = (const float*)d_in[15];
    const float* bo       = (const float*)d_in[16];
    const float* W1       = (const float*)d_in[17];
    const float* b1       = (const float*)d_in[18];
    const float* W2       = (const float*)d_in[19];
    const float* b2       = (const float*)d_in[20];

    char* ws = (char*)d_ws;
    float* h    = (float*)ws;                      ws += (size_t)NT * DIM * 4;        // 4 MB
    float* hn   = (float*)ws;                      ws += (size_t)NT * DIM * 4;        // 4 MB (also attn-out O)
    float* ffn  = (float*)ws;                      ws += (size_t)NT * FFD * 4;        // 16 MB (also qkv buf)
    float* Bg   = (float*)ws;                      ws += (size_t)NG * 1024 * 4;       // 256 KB
    float* Wqkv = (float*)ws;                      ws += (size_t)NLAY * DIM * 1536 * 4; // 12 MB
    float* bqkv = (float*)ws;                      ws += (size_t)NLAY * 1536 * 4;
    float* qkv = ffn;   // alias: qkv dead before ffn written, and vice versa
    float* o   = hn;    // alias: hn dead after QKV gemm, o dead before next LN

    build_B<<<NG, 256, 0, stream>>>(sp, db, vbias, Bg);
    init_h<<<NT, 256, 0, stream>>>(x, degrees, init_W, init_b, cent_emb, h);
    rearrange_qkv<<<(NLAY * DIM * 1536 + 255) / 256, 256, 0, stream>>>(
        Wq, Wk, Wv, bq, bk, bv, Wqkv, bqkv);

    for (int l = 0; l < NLAY; ++l) {
        layernorm<<<NT, 256, 0, stream>>>(h, hn);
        dim3 g1(1536 / 64, NT / 64);
        gemm_f32<<<g1, 256, 0, stream>>>(hn, Wqkv + (size_t)l * DIM * 1536,
                                         bqkv + (size_t)l * 1536, nullptr,
                                         qkv, NT, 1536, DIM, 0);
        attention<<<NG * NHD, 256, 0, stream>>>(qkv, Bg, o);
        dim3 g2(DIM / 64, NT / 64);
        gemm_f32<<<g2, 256, 0, stream>>>(o, Wo + (size_t)l * DIM * DIM,
                                         bo + (size_t)l * DIM, h,
                                         h, NT, DIM, DIM, 0);
        layernorm<<<NT, 256, 0, stream>>>(h, hn);
        dim3 g3(FFD / 64, NT / 64);
        gemm_f32<<<g3, 256, 0, stream>>>(hn, W1 + (size_t)l * DIM * FFD,
                                         b1 + (size_t)l * FFD, nullptr,
                                         ffn, NT, FFD, DIM, 1);
        dim3 g4(DIM / 64, NT / 64);
        gemm_f32<<<g4, 256, 0, stream>>>(ffn, W2 + (size_t)l * FFD * DIM,
                                         b2 + (size_t)l * DIM, h,
                                         h, NT, DIM, FFD, 0);
    }

    hipMemcpyAsync(d_out, h + (size_t)NORI * DIM, (size_t)NG * DIM * sizeof(float),
                   hipMemcpyDeviceToDevice, stream);
}

// Round 2
// 743.097 us; speedup vs baseline: 2.0555x; 2.0555x over previous
//
#include <hip/hip_runtime.h>

// Graphormer encoder — bf16 MFMA GEMMs, fp32 residual path.
// Attention is block-diagonal (64 graphs x 32 nodes) — never materialize [N,N].

#define NG   64
#define NP   31
#define NORI 1984
#define NT   2048
#define DIM  512
#define NHD  8
#define DKH  64
#define FFD  2048
#define NLAY 4
#define NFEA 32

typedef __attribute__((ext_vector_type(8))) short short8;
typedef __attribute__((ext_vector_type(4))) float floatx4;

__device__ __forceinline__ unsigned short f2bf(float f) {
    union { float f; unsigned u; } v; v.f = f;
    unsigned r = v.u + 0x7fffu + ((v.u >> 16) & 1u);
    return (unsigned short)(r >> 16);
}
__device__ __forceinline__ float bf2f(unsigned short u) {
    union { unsigned u; float f; } v; v.u = ((unsigned)u) << 16;
    return v.f;
}

// ---------------------------------------------------------------- build B blocks
__global__ __launch_bounds__(256) void build_B(
    const int* __restrict__ sp, const float* __restrict__ db,
    const float* __restrict__ virt_bias, float* __restrict__ Bg)
{
    int g = blockIdx.x;
    float vb = virt_bias[0];
    for (int e = threadIdx.x; e < 1024; e += 256) {
        int i = e >> 5, j = e & 31;
        float v;
        if (i == j) v = db[0];
        else if (i < NP && j < NP) {
            int s = sp[(size_t)(g * NP + i) * NORI + g * NP + j];
            v = db[s < 100 ? s : 100];
        } else v = vb;
        Bg[(size_t)g * 1024 + e] = v;
    }
}

// ---------------------------------------------------------------- init h (fp32)
__global__ __launch_bounds__(256) void init_h(
    const float* __restrict__ x, const int* __restrict__ degrees,
    const float* __restrict__ init_W, const float* __restrict__ init_b,
    const float* __restrict__ cent_emb, float* __restrict__ h)
{
    int n = blockIdx.x;
    int tid = threadIdx.x;
    __shared__ float xs[NFEA];
    if (n < NORI && tid < NFEA) xs[tid] = x[(size_t)n * NFEA + tid];
    __syncthreads();
    int deg = degrees[n]; if (deg > 100) deg = 100;
    for (int d = tid; d < DIM; d += 256) {
        float v = cent_emb[(size_t)deg * DIM + d];
        if (n < NORI) {
            float acc = init_b[d];
            #pragma unroll
            for (int k = 0; k < NFEA; ++k) acc += xs[k] * init_W[(size_t)k * DIM + d];
            v += acc;
        }
        h[(size_t)n * DIM + d] = v;
    }
}

// ---------------------------------------------------------------- weight prep
// QKV: Wq/Wk/Wv [L,H,D,DK] -> Wqkv_t [L][1536][512] bf16 (row = which*512+h*64+k, col = d)
__global__ __launch_bounds__(256) void qkv_prep(
    const float* __restrict__ Wq, const float* __restrict__ Wk, const float* __restrict__ Wv,
    unsigned short* __restrict__ Wt)
{
    int tile = blockIdx.x;          // 96 slices * 32 tiles
    int slice = tile >> 5;
    int tloc = tile & 31;
    int dt = tloc >> 1, kt = tloc & 1;
    int l = slice / 24; int rem = slice % 24; int which = rem >> 3; int hh = rem & 7;
    const float* W = (which == 0) ? Wq : (which == 1) ? Wk : Wv;
    const float* in = W + (size_t)(l * 8 + hh) * DIM * DKH;
    __shared__ float tl[32][33];
    int tr = threadIdx.x >> 5, tc = threadIdx.x & 31;
    #pragma unroll
    for (int p = 0; p < 4; ++p)
        tl[tr + p * 8][tc] = in[(size_t)(dt * 32 + tr + p * 8) * DKH + kt * 32 + tc];
    __syncthreads();
    unsigned short* out = Wt + ((size_t)l * 1536 + which * 512 + hh * 64 + kt * 32) * DIM + dt * 32;
    #pragma unroll
    for (int p = 0; p < 4; ++p)
        out[(size_t)(tr + p * 8) * DIM + tc] = f2bf(tl[tc][tr + p * 8]);
}

__global__ __launch_bounds__(256) void bias_prep(
    const float* __restrict__ bq, const float* __restrict__ bk, const float* __restrict__ bv,
    float* __restrict__ bqkv)
{
    int idx = blockIdx.x * 256 + threadIdx.x;
    if (idx >= NLAY * 1536) return;
    int l = idx / 1536, c = idx % 1536;
    int which = c >> 9, cc = c & 511;
    const float* b = (which == 0) ? bq : (which == 1) ? bk : bv;
    bqkv[idx] = b[(size_t)l * 512 + cc];
}

// generic per-layer transpose: in [L][R][C] fp32 -> out [L][C][R] bf16
__global__ __launch_bounds__(256) void transpose_bf16(
    const float* __restrict__ in, unsigned short* __restrict__ out, int R, int C)
{
    int l = blockIdx.z;
    const float* ip = in + (size_t)l * R * C;
    unsigned short* op = out + (size_t)l * R * C;
    int r0 = blockIdx.y * 32, c0 = blockIdx.x * 32;
    __shared__ float tl[32][33];
    int tr = threadIdx.x >> 5, tc = threadIdx.x & 31;
    #pragma unroll
    for (int p = 0; p < 4; ++p)
        tl[tr + p * 8][tc] = ip[(size_t)(r0 + tr + p * 8) * C + c0 + tc];
    __syncthreads();
    #pragma unroll
    for (int p = 0; p < 4; ++p)
        op[(size_t)(c0 + tr + p * 8) * R + r0 + tc] = f2bf(tl[tc][tr + p * 8]);
}

// ---------------------------------------------------------------- layernorm: fp32 in -> bf16 out
__global__ __launch_bounds__(256) void layernorm_bf16(
    const float* __restrict__ in, unsigned short* __restrict__ out)
{
    int n = blockIdx.x;
    int tid = threadIdx.x;
    const float* row = in + (size_t)n * DIM;
    float v0 = row[tid], v1 = row[tid + 256];
    float s = v0 + v1;
    float sq = v0 * v0 + v1 * v1;
    #pragma unroll
    for (int off = 32; off > 0; off >>= 1) {
        s  += __shfl_down(s, off);
        sq += __shfl_down(sq, off);
    }
    __shared__ float red[8];
    int wave = tid >> 6;
    if ((tid & 63) == 0) { red[wave] = s; red[4 + wave] = sq; }
    __syncthreads();
    float ts  = red[0] + red[1] + red[2] + red[3];
    float tsq = red[4] + red[5] + red[6] + red[7];
    float m   = ts * (1.0f / DIM);
    float var = tsq * (1.0f / DIM) - m * m;
    float inv = rsqrtf(var + 1e-5f);
    out[(size_t)n * DIM + tid]       = f2bf((v0 - m) * inv);
    out[(size_t)n * DIM + tid + 256] = f2bf((v1 - m) * inv);
}

// ---------------------------------------------------------------- bf16 MFMA GEMM
// C[M,N] = A[M,K] @ Bt[N,K]^T + bias (+relu) (+resid). Tile 128x64x64, 256 thr.
// flags: 1 = relu, 2 = bf16 output
__global__ __launch_bounds__(256) void gemm_bf16(
    const unsigned short* __restrict__ A, const unsigned short* __restrict__ Bt,
    const float* __restrict__ bias, const float* __restrict__ resid,
    void* __restrict__ out, int M, int N, int K, int flags)
{
    __shared__ __align__(16) unsigned short Asl[128 * 72];
    __shared__ __align__(16) unsigned short Bsl[64 * 72];
    int tid = threadIdx.x;
    int row0 = blockIdx.y * 128, col0 = blockIdx.x * 64;
    int wave = tid >> 6, lane = tid & 63;
    int quad = lane >> 4, m16 = lane & 15;
    int mw = (wave >> 1) * 64, nw = (wave & 1) * 32;
    floatx4 acc[4][2] = {};
    for (int k0 = 0; k0 < K; k0 += 64) {
        #pragma unroll
        for (int p = 0; p < 4; ++p) {
            int idx = (p * 256 + tid) * 8;
            int r = idx >> 6, kk = idx & 63;
            *(float4*)(Asl + r * 72 + kk) =
                *(const float4*)(A + (size_t)(row0 + r) * K + k0 + kk);
        }
        #pragma unroll
        for (int p = 0; p < 2; ++p) {
            int idx = (p * 256 + tid) * 8;
            int r = idx >> 6, kk = idx & 63;
            *(float4*)(Bsl + r * 72 + kk) =
                *(const float4*)(Bt + (size_t)(col0 + r) * K + k0 + kk);
        }
        __syncthreads();
        #pragma unroll
        for (int ks = 0; ks < 64; ks += 32) {
            short8 a[4], b[2];
            #pragma unroll
            for (int mi = 0; mi < 4; ++mi)
                a[mi] = *(const short8*)(Asl + (mw + mi * 16 + m16) * 72 + ks + quad * 8);
            #pragma unroll
            for (int ni = 0; ni < 2; ++ni)
                b[ni] = *(const short8*)(Bsl + (nw + ni * 16 + m16) * 72 + ks + quad * 8);
            #pragma unroll
            for (int mi = 0; mi < 4; ++mi)
                #pragma unroll
                for (int ni = 0; ni < 2; ++ni)
                    acc[mi][ni] = __builtin_amdgcn_mfma_f32_16x16x32_bf16(
                        a[mi], b[ni], acc[mi][ni], 0, 0, 0);
        }
        __syncthreads();
    }
    int do_relu = flags & 1, out_bf = flags & 2;
    #pragma unroll
    for (int mi = 0; mi < 4; ++mi) {
        #pragma unroll
        for (int ni = 0; ni < 2; ++ni) {
            int col = col0 + nw + ni * 16 + m16;
            float bval = bias ? bias[col] : 0.0f;
            #pragma unroll
            for (int rr = 0; rr < 4; ++rr) {
                int row = row0 + mw + mi * 16 + quad * 4 + rr;
                float v = acc[mi][ni][rr] + bval;
                if (do_relu) v = fmaxf(v, 0.0f);
                if (resid) v += resid[(size_t)row * N + col];
                if (out_bf) ((unsigned short*)out)[(size_t)row * N + col] = f2bf(v);
                else        ((float*)out)[(size_t)row * N + col] = v;
            }
        }
    }
}

// ---------------------------------------------------------------- block attention (bf16 io)
__global__ __launch_bounds__(256) void attention(
    const unsigned short* __restrict__ qkv,  // [NT][1536] bf16, Q|K|V head-major
    const float* __restrict__ Bg,            // [NG][32][32]
    unsigned short* __restrict__ O)          // [NT][512] bf16 head-major
{
    int g = blockIdx.x >> 3;
    int hh = blockIdx.x & 7;
    __shared__ float Qs[32][64], Ks[32][64], Vs[32][64];
    __shared__ float S[32][32];
    int tid = threadIdx.x;
    int i = tid >> 3;
    int c0 = (tid & 7) * 8;
    int gn = (i < NP) ? g * NP + i : NORI + g;
    const unsigned short* base = qkv + (size_t)gn * 1536 + hh * DKH;
    short8 qv = *(const short8*)(base + c0);
    short8 kv = *(const short8*)(base + 512 + c0);
    short8 vv = *(const short8*)(base + 1024 + c0);
    #pragma unroll
    for (int j = 0; j < 8; ++j) {
        Qs[i][c0 + j] = bf2f((unsigned short)qv[j]);
        Ks[i][c0 + j] = bf2f((unsigned short)kv[j]);
        Vs[i][c0 + j] = bf2f((unsigned short)vv[j]);
    }
    __syncthreads();
    const float scale = 0.125f;  // 1/sqrt(64)
    #pragma unroll
    for (int e = 0; e < 4; ++e) {
        int idx = tid + e * 256;
        int si = idx >> 5, sj = idx & 31;
        float dot = 0.0f;
        #pragma unroll
        for (int k = 0; k < DKH; ++k) dot += Qs[si][k] * Ks[sj][k];
        S[si][sj] = dot * scale + Bg[(size_t)g * 1024 + si * 32 + sj];
    }
    __syncthreads();
    if (tid < 32) {
        float mx = -1e30f;
        #pragma unroll
        for (int j = 0; j < 32; ++j) mx = fmaxf(mx, S[tid][j]);
        float sum = 0.0f;
        #pragma unroll
        for (int j = 0; j < 32; ++j) { float e = __expf(S[tid][j] - mx); S[tid][j] = e; sum += e; }
        float inv = 1.0f / sum;
        #pragma unroll
        for (int j = 0; j < 32; ++j) S[tid][j] *= inv;
    }
    __syncthreads();
    short8 ov;
    #pragma unroll
    for (int cc = 0; cc < 8; ++cc) {
        float acc = 0.0f;
        #pragma unroll
        for (int j = 0; j < 32; ++j) acc += S[i][j] * Vs[j][c0 + cc];
        ov[cc] = (short)f2bf(acc);
    }
    *(short8*)(O + (size_t)gn * DIM + hh * DKH + c0) = ov;
}

// ---------------------------------------------------------------- launch
extern "C" void kernel_launch(void* const* d_in, const int* in_sizes, int n_in,
                              void* d_out, int out_size, void* d_ws, size_t ws_size,
                              hipStream_t stream)
{
    const float* x        = (const float*)d_in[0];
    const int*   sp       = (const int*)d_in[1];
    const int*   degrees  = (const int*)d_in[3];
    const float* init_W   = (const float*)d_in[4];
    const float* init_b   = (const float*)d_in[5];
    const float* cent_emb = (const float*)d_in[6];
    const float* db       = (const float*)d_in[7];
    const float* vbias    = (const float*)d_in[8];
    const float* Wq       = (const float*)d_in[9];
    const float* bq       = (const float*)d_in[10];
    const float* Wk       = (const float*)d_in[11];
    const float* bk       = (const float*)d_in[12];
    const float* Wv       = (const float*)d_in[13];
    const float* bv       = (const float*)d_in[14];
    const float* Wo       = (const float*)d_in[15];
    const float* bo       = (const float*)d_in[16];
    const float* W1       = (const float*)d_in[17];
    const float* b1       = (const float*)d_in[18];
    const float* W2       = (const float*)d_in[19];
    const float* b2       = (const float*)d_in[20];

    char* ws = (char*)d_ws;
    float*          h      = (float*)ws;          ws += (size_t)NT * DIM * 4;       // 4 MB
    unsigned short* hn     = (unsigned short*)ws; ws += (size_t)NT * DIM * 2;       // 2 MB
    unsigned short* o      = (unsigned short*)ws; ws += (size_t)NT * DIM * 2;       // 2 MB
    unsigned short* qkv    = (unsigned short*)ws; ws += (size_t)NT * FFD * 2;       // 8 MB (aliased: qkv / ffn)
    float*          Bg     = (float*)ws;          ws += (size_t)NG * 1024 * 4;      // 256 KB
    unsigned short* Wqkv_t = (unsigned short*)ws; ws += (size_t)NLAY * 1536 * DIM * 2; // 6 MB
    unsigned short* Wo_t   = (unsigned short*)ws; ws += (size_t)NLAY * DIM * DIM * 2;  // 2 MB
    unsigned short* W1_t   = (unsigned short*)ws; ws += (size_t)NLAY * FFD * DIM * 2;  // 8 MB
    unsigned short* W2_t   = (unsigned short*)ws; ws += (size_t)NLAY * DIM * FFD * 2;  // 8 MB
    float*          bqkv   = (float*)ws;          ws += (size_t)NLAY * 1536 * 4;
    unsigned short* ffnb   = qkv;  // alias: qkv dead after attention, ffnb dead after GEMM4

    // prep
    build_B<<<NG, 256, 0, stream>>>(sp, db, vbias, Bg);
    init_h<<<NT, 256, 0, stream>>>(x, degrees, init_W, init_b, cent_emb, h);
    qkv_prep<<<96 * 32, 256, 0, stream>>>(Wq, Wk, Wv, Wqkv_t);
    bias_prep<<<(NLAY * 1536 + 255) / 256, 256, 0, stream>>>(bq, bk, bv, bqkv);
    transpose_bf16<<<dim3(DIM / 32, DIM / 32, NLAY), 256, 0, stream>>>(Wo, Wo_t, DIM, DIM);
    transpose_bf16<<<dim3(FFD / 32, DIM / 32, NLAY), 256, 0, stream>>>(W1, W1_t, DIM, FFD);
    transpose_bf16<<<dim3(DIM / 32, FFD / 32, NLAY), 256, 0, stream>>>(W2, W2_t, FFD, DIM);

    for (int l = 0; l < NLAY; ++l) {
        layernorm_bf16<<<NT, 256, 0, stream>>>(h, hn);
        gemm_bf16<<<dim3(1536 / 64, NT / 128), 256, 0, stream>>>(
            hn, Wqkv_t + (size_t)l * 1536 * DIM, bqkv + (size_t)l * 1536, nullptr,
            qkv, NT, 1536, DIM, /*bf16 out*/2);
        attention<<<NG * NHD, 256, 0, stream>>>(qkv, Bg, o);
        gemm_bf16<<<dim3(DIM / 64, NT / 128), 256, 0, stream>>>(
            o, Wo_t + (size_t)l * DIM * DIM, bo + (size_t)l * DIM, h,
            h, NT, DIM, DIM, /*fp32 out*/0);
        layernorm_bf16<<<NT, 256, 0, stream>>>(h, hn);
        gemm_bf16<<<dim3(FFD / 64, NT / 128), 256, 0, stream>>>(
            hn, W1_t + (size_t)l * FFD * DIM, b1 + (size_t)l * FFD, nullptr,
            ffnb, NT, FFD, DIM, /*relu + bf16 out*/3);
        gemm_bf16<<<dim3(DIM / 64, NT / 128), 256, 0, stream>>>(
            ffnb, W2_t + (size_t)l * DIM * FFD, b2 + (size_t)l * DIM, h,
            h, NT, DIM, FFD, /*fp32 out*/0);
    }

    hipMemcpyAsync(d_out, h + (size_t)NORI * DIM, (size_t)NG * DIM * sizeof(float),
                   hipMemcpyDeviceToDevice, stream);
}

// Round 3
// 613.981 us; speedup vs baseline: 2.4877x; 1.2103x over previous
//
#include <hip/hip_runtime.h>

// Graphormer encoder — bf16 MFMA GEMMs, fp32 residual path.
// Attention is block-diagonal (64 graphs x 32 nodes) — never materialize [N,N].

#define NG   64
#define NP   31
#define NORI 1984
#define NT   2048
#define DIM  512
#define NHD  8
#define DKH  64
#define FFD  2048
#define NLAY 4
#define NFEA 32

typedef __attribute__((ext_vector_type(8))) short short8;
typedef __attribute__((ext_vector_type(4))) float floatx4;

__device__ __forceinline__ unsigned short f2bf(float f) {
    union { float f; unsigned u; } v; v.f = f;
    unsigned r = v.u + 0x7fffu + ((v.u >> 16) & 1u);
    return (unsigned short)(r >> 16);
}
__device__ __forceinline__ float bf2f(unsigned short u) {
    union { unsigned u; float f; } v; v.u = ((unsigned)u) << 16;
    return v.f;
}

// ---------------------------------------------------------------- build B blocks
__global__ __launch_bounds__(256) void build_B(
    const int* __restrict__ sp, const float* __restrict__ db,
    const float* __restrict__ virt_bias, float* __restrict__ Bg)
{
    int g = blockIdx.x;
    float vb = virt_bias[0];
    for (int e = threadIdx.x; e < 1024; e += 256) {
        int i = e >> 5, j = e & 31;
        float v;
        if (i == j) v = db[0];
        else if (i < NP && j < NP) {
            int s = sp[(size_t)(g * NP + i) * NORI + g * NP + j];
            v = db[s < 100 ? s : 100];
        } else v = vb;
        Bg[(size_t)g * 1024 + e] = v;
    }
}

// ---------------------------------------------------------------- init h (fp32)
__global__ __launch_bounds__(256) void init_h(
    const float* __restrict__ x, const int* __restrict__ degrees,
    const float* __restrict__ init_W, const float* __restrict__ init_b,
    const float* __restrict__ cent_emb, float* __restrict__ h)
{
    int n = blockIdx.x;
    int tid = threadIdx.x;
    __shared__ float xs[NFEA];
    if (n < NORI && tid < NFEA) xs[tid] = x[(size_t)n * NFEA + tid];
    __syncthreads();
    int deg = degrees[n]; if (deg > 100) deg = 100;
    for (int d = tid; d < DIM; d += 256) {
        float v = cent_emb[(size_t)deg * DIM + d];
        if (n < NORI) {
            float acc = init_b[d];
            #pragma unroll
            for (int k = 0; k < NFEA; ++k) acc += xs[k] * init_W[(size_t)k * DIM + d];
            v += acc;
        }
        h[(size_t)n * DIM + d] = v;
    }
}

// ---------------------------------------------------------------- weight prep
// QKV: Wq/Wk/Wv [L,H,D,DK] -> Wqkv_t [L][1536][512] bf16 (row = which*512+h*64+k, col = d)
__global__ __launch_bounds__(256) void qkv_prep(
    const float* __restrict__ Wq, const float* __restrict__ Wk, const float* __restrict__ Wv,
    unsigned short* __restrict__ Wt)
{
    int tile = blockIdx.x;          // 96 slices * 32 tiles
    int slice = tile >> 5;
    int tloc = tile & 31;
    int dt = tloc >> 1, kt = tloc & 1;
    int l = slice / 24; int rem = slice % 24; int which = rem >> 3; int hh = rem & 7;
    const float* W = (which == 0) ? Wq : (which == 1) ? Wk : Wv;
    const float* in = W + (size_t)(l * 8 + hh) * DIM * DKH;
    __shared__ float tl[32][33];
    int tr = threadIdx.x >> 5, tc = threadIdx.x & 31;
    #pragma unroll
    for (int p = 0; p < 4; ++p)
        tl[tr + p * 8][tc] = in[(size_t)(dt * 32 + tr + p * 8) * DKH + kt * 32 + tc];
    __syncthreads();
    unsigned short* out = Wt + ((size_t)l * 1536 + which * 512 + hh * 64 + kt * 32) * DIM + dt * 32;
    #pragma unroll
    for (int p = 0; p < 4; ++p)
        out[(size_t)(tr + p * 8) * DIM + tc] = f2bf(tl[tc][tr + p * 8]);
}

__global__ __launch_bounds__(256) void bias_prep(
    const float* __restrict__ bq, const float* __restrict__ bk, const float* __restrict__ bv,
    float* __restrict__ bqkv)
{
    int idx = blockIdx.x * 256 + threadIdx.x;
    if (idx >= NLAY * 1536) return;
    int l = idx / 1536, c = idx % 1536;
    int which = c >> 9, cc = c & 511;
    const float* b = (which == 0) ? bq : (which == 1) ? bk : bv;
    bqkv[idx] = b[(size_t)l * 512 + cc];
}

// generic per-layer transpose: in [L][R][C] fp32 -> out [L][C][R] bf16
__global__ __launch_bounds__(256) void transpose_bf16(
    const float* __restrict__ in, unsigned short* __restrict__ out, int R, int C)
{
    int l = blockIdx.z;
    const float* ip = in + (size_t)l * R * C;
    unsigned short* op = out + (size_t)l * R * C;
    int r0 = blockIdx.y * 32, c0 = blockIdx.x * 32;
    __shared__ float tl[32][33];
    int tr = threadIdx.x >> 5, tc = threadIdx.x & 31;
    #pragma unroll
    for (int p = 0; p < 4; ++p)
        tl[tr + p * 8][tc] = ip[(size_t)(r0 + tr + p * 8) * C + c0 + tc];
    __syncthreads();
    #pragma unroll
    for (int p = 0; p < 4; ++p)
        op[(size_t)(c0 + tr + p * 8) * R + r0 + tc] = f2bf(tl[tc][tr + p * 8]);
}

// ---------------------------------------------------------------- layernorm: fp32 in -> bf16 out
__global__ __launch_bounds__(256) void layernorm_bf16(
    const float* __restrict__ in, unsigned short* __restrict__ out)
{
    int n = blockIdx.x;
    int tid = threadIdx.x;
    const float* row = in + (size_t)n * DIM;
    float v0 = row[tid], v1 = row[tid + 256];
    float s = v0 + v1;
    float sq = v0 * v0 + v1 * v1;
    #pragma unroll
    for (int off = 32; off > 0; off >>= 1) {
        s  += __shfl_down(s, off);
        sq += __shfl_down(sq, off);
    }
    __shared__ float red[8];
    int wave = tid >> 6;
    if ((tid & 63) == 0) { red[wave] = s; red[4 + wave] = sq; }
    __syncthreads();
    float ts  = red[0] + red[1] + red[2] + red[3];
    float tsq = red[4] + red[5] + red[6] + red[7];
    float m   = ts * (1.0f / DIM);
    float var = tsq * (1.0f / DIM) - m * m;
    float inv = rsqrtf(var + 1e-5f);
    out[(size_t)n * DIM + tid]       = f2bf((v0 - m) * inv);
    out[(size_t)n * DIM + tid + 256] = f2bf((v1 - m) * inv);
}

// ---------------------------------------------------------------- bf16 MFMA GEMM
// C[M,N] = A[M,K] @ Bt[N,K]^T + bias (+relu) (+resid). Tile BMx64x64, 256 thr.
// BM=128: wave=64x32 (4x2 frags). BM=64: wave=32x32 (2x2 frags).
// flags: 1 = relu, 2 = bf16 output
template<int BM>
__global__ __launch_bounds__(256) void gemm_bf16(
    const unsigned short* __restrict__ A, const unsigned short* __restrict__ Bt,
    const float* __restrict__ bias, const float* __restrict__ resid,
    void* __restrict__ out, int M, int N, int K, int flags)
{
    constexpr int FM = BM / 32;   // M-frags per wave
    __shared__ __align__(16) unsigned short Asl[BM * 72];
    __shared__ __align__(16) unsigned short Bsl[64 * 72];
    int tid = threadIdx.x;
    int row0 = blockIdx.y * BM, col0 = blockIdx.x * 64;
    int wave = tid >> 6, lane = tid & 63;
    int quad = lane >> 4, m16 = lane & 15;
    int mw = (wave >> 1) * (BM / 2), nw = (wave & 1) * 32;
    floatx4 acc[FM][2] = {};
    for (int k0 = 0; k0 < K; k0 += 64) {
        #pragma unroll
        for (int p = 0; p < BM / 32; ++p) {
            int idx = (p * 256 + tid) * 8;
            int r = idx >> 6, kk = idx & 63;
            *(float4*)(Asl + r * 72 + kk) =
                *(const float4*)(A + (size_t)(row0 + r) * K + k0 + kk);
        }
        #pragma unroll
        for (int p = 0; p < 2; ++p) {
            int idx = (p * 256 + tid) * 8;
            int r = idx >> 6, kk = idx & 63;
            *(float4*)(Bsl + r * 72 + kk) =
                *(const float4*)(Bt + (size_t)(col0 + r) * K + k0 + kk);
        }
        __syncthreads();
        #pragma unroll
        for (int ks = 0; ks < 64; ks += 32) {
            short8 a[FM], b[2];
            #pragma unroll
            for (int mi = 0; mi < FM; ++mi)
                a[mi] = *(const short8*)(Asl + (mw + mi * 16 + m16) * 72 + ks + quad * 8);
            #pragma unroll
            for (int ni = 0; ni < 2; ++ni)
                b[ni] = *(const short8*)(Bsl + (nw + ni * 16 + m16) * 72 + ks + quad * 8);
            #pragma unroll
            for (int mi = 0; mi < FM; ++mi)
                #pragma unroll
                for (int ni = 0; ni < 2; ++ni)
                    acc[mi][ni] = __builtin_amdgcn_mfma_f32_16x16x32_bf16(
                        a[mi], b[ni], acc[mi][ni], 0, 0, 0);
        }
        __syncthreads();
    }
    int do_relu = flags & 1, out_bf = flags & 2;
    #pragma unroll
    for (int mi = 0; mi < FM; ++mi) {
        #pragma unroll
        for (int ni = 0; ni < 2; ++ni) {
            int col = col0 + nw + ni * 16 + m16;
            float bval = bias ? bias[col] : 0.0f;
            #pragma unroll
            for (int rr = 0; rr < 4; ++rr) {
                int row = row0 + mw + mi * 16 + quad * 4 + rr;
                float v = acc[mi][ni][rr] + bval;
                if (do_relu) v = fmaxf(v, 0.0f);
                if (resid) v += resid[(size_t)row * N + col];
                if (out_bf) ((unsigned short*)out)[(size_t)row * N + col] = f2bf(v);
                else        ((float*)out)[(size_t)row * N + col] = v;
            }
        }
    }
}

// ---------------------------------------------------------------- block attention (bf16 io)
// Padded LDS strides (65 / 33) -> conflict-free: Ks bank = (sj+k)%32 over sj.
__global__ __launch_bounds__(256) void attention(
    const unsigned short* __restrict__ qkv,  // [NT][1536] bf16, Q|K|V head-major
    const float* __restrict__ Bg,            // [NG][32][32]
    unsigned short* __restrict__ O)          // [NT][512] bf16 head-major
{
    int g = blockIdx.x >> 3;
    int hh = blockIdx.x & 7;
    __shared__ float Qs[32][65], Ks[32][65], Vs[32][65];
    __shared__ float S[32][33];
    int tid = threadIdx.x;
    int i = tid >> 3;
    int c0 = (tid & 7) * 8;
    int gn = (i < NP) ? g * NP + i : NORI + g;
    const unsigned short* base = qkv + (size_t)gn * 1536 + hh * DKH;
    short8 qv = *(const short8*)(base + c0);
    short8 kv = *(const short8*)(base + 512 + c0);
    short8 vv = *(const short8*)(base + 1024 + c0);
    #pragma unroll
    for (int j = 0; j < 8; ++j) {
        Qs[i][c0 + j] = bf2f((unsigned short)qv[j]);
        Ks[i][c0 + j] = bf2f((unsigned short)kv[j]);
        Vs[i][c0 + j] = bf2f((unsigned short)vv[j]);
    }
    __syncthreads();
    const float scale = 0.125f;  // 1/sqrt(64)
    #pragma unroll
    for (int e = 0; e < 4; ++e) {
        int idx = tid + e * 256;
        int si = idx >> 5, sj = idx & 31;
        float dot = 0.0f;
        #pragma unroll
        for (int k = 0; k < DKH; ++k) dot += Qs[si][k] * Ks[sj][k];
        S[si][sj] = dot * scale + Bg[(size_t)g * 1024 + si * 32 + sj];
    }
    __syncthreads();
    if (tid < 32) {
        float mx = -1e30f;
        #pragma unroll
        for (int j = 0; j < 32; ++j) mx = fmaxf(mx, S[tid][j]);
        float sum = 0.0f;
        #pragma unroll
        for (int j = 0; j < 32; ++j) { float e = __expf(S[tid][j] - mx); S[tid][j] = e; sum += e; }
        float inv = 1.0f / sum;
        #pragma unroll
        for (int j = 0; j < 32; ++j) S[tid][j] *= inv;
    }
    __syncthreads();
    short8 ov;
    #pragma unroll
    for (int cc = 0; cc < 8; ++cc) {
        float acc = 0.0f;
        #pragma unroll
        for (int j = 0; j < 32; ++j) acc += S[i][j] * Vs[j][c0 + cc];
        ov[cc] = (short)f2bf(acc);
    }
    *(short8*)(O + (size_t)gn * DIM + hh * DKH + c0) = ov;
}

// ---------------------------------------------------------------- launch
extern "C" void kernel_launch(void* const* d_in, const int* in_sizes, int n_in,
                              void* d_out, int out_size, void* d_ws, size_t ws_size,
                              hipStream_t stream)
{
    const float* x        = (const float*)d_in[0];
    const int*   sp       = (const int*)d_in[1];
    const int*   degrees  = (const int*)d_in[3];
    const float* init_W   = (const float*)d_in[4];
    const float* init_b   = (const float*)d_in[5];
    const float* cent_emb = (const float*)d_in[6];
    const float* db       = (const float*)d_in[7];
    const float* vbias    = (const float*)d_in[8];
    const float* Wq       = (const float*)d_in[9];
    const float* bq       = (const float*)d_in[10];
    const float* Wk       = (const float*)d_in[11];
    const float* bk       = (const float*)d_in[12];
    const float* Wv       = (const float*)d_in[13];
    const float* bv       = (const float*)d_in[14];
    const float* Wo       = (const float*)d_in[15];
    const float* bo       = (const float*)d_in[16];
    const float* W1       = (const float*)d_in[17];
    const float* b1       = (const float*)d_in[18];
    const float* W2       = (const float*)d_in[19];
    const float* b2       = (const float*)d_in[20];

    char* ws = (char*)d_ws;
    float*          h      = (float*)ws;          ws += (size_t)NT * DIM * 4;       // 4 MB
    unsigned short* hn     = (unsigned short*)ws; ws += (size_t)NT * DIM * 2;       // 2 MB
    unsigned short* o      = (unsigned short*)ws; ws += (size_t)NT * DIM * 2;       // 2 MB
    unsigned short* qkv    = (unsigned short*)ws; ws += (size_t)NT * FFD * 2;       // 8 MB (aliased: qkv / ffn)
    float*          Bg     = (float*)ws;          ws += (size_t)NG * 1024 * 4;      // 256 KB
    unsigned short* Wqkv_t = (unsigned short*)ws; ws += (size_t)NLAY * 1536 * DIM * 2; // 6 MB
    unsigned short* Wo_t   = (unsigned short*)ws; ws += (size_t)NLAY * DIM * DIM * 2;  // 2 MB
    unsigned short* W1_t   = (unsigned short*)ws; ws += (size_t)NLAY * FFD * DIM * 2;  // 8 MB
    unsigned short* W2_t   = (unsigned short*)ws; ws += (size_t)NLAY * DIM * FFD * 2;  // 8 MB
    float*          bqkv   = (float*)ws;          ws += (size_t)NLAY * 1536 * 4;
    unsigned short* ffnb   = qkv;  // alias: qkv dead after attention, ffnb dead after GEMM4

    // prep
    build_B<<<NG, 256, 0, stream>>>(sp, db, vbias, Bg);
    init_h<<<NT, 256, 0, stream>>>(x, degrees, init_W, init_b, cent_emb, h);
    qkv_prep<<<96 * 32, 256, 0, stream>>>(Wq, Wk, Wv, Wqkv_t);
    bias_prep<<<(NLAY * 1536 + 255) / 256, 256, 0, stream>>>(bq, bk, bv, bqkv);
    transpose_bf16<<<dim3(DIM / 32, DIM / 32, NLAY), 256, 0, stream>>>(Wo, Wo_t, DIM, DIM);
    transpose_bf16<<<dim3(FFD / 32, DIM / 32, NLAY), 256, 0, stream>>>(W1, W1_t, DIM, FFD);
    transpose_bf16<<<dim3(DIM / 32, FFD / 32, NLAY), 256, 0, stream>>>(W2, W2_t, FFD, DIM);

    for (int l = 0; l < NLAY; ++l) {
        layernorm_bf16<<<NT, 256, 0, stream>>>(h, hn);
        gemm_bf16<128><<<dim3(1536 / 64, NT / 128), 256, 0, stream>>>(
            hn, Wqkv_t + (size_t)l * 1536 * DIM, bqkv + (size_t)l * 1536, nullptr,
            qkv, NT, 1536, DIM, /*bf16 out*/2);
        attention<<<NG * NHD, 256, 0, stream>>>(qkv, Bg, o);
        gemm_bf16<64><<<dim3(DIM / 64, NT / 64), 256, 0, stream>>>(
            o, Wo_t + (size_t)l * DIM * DIM, bo + (size_t)l * DIM, h,
            h, NT, DIM, DIM, /*fp32 out*/0);
        layernorm_bf16<<<NT, 256, 0, stream>>>(h, hn);
        gemm_bf16<128><<<dim3(FFD / 64, NT / 128), 256, 0, stream>>>(
            hn, W1_t + (size_t)l * FFD * DIM, b1 + (size_t)l * FFD, nullptr,
            ffnb, NT, FFD, DIM, /*relu + bf16 out*/3);
        gemm_bf16<64><<<dim3(DIM / 64, NT / 64), 256, 0, stream>>>(
            ffnb, W2_t + (size_t)l * DIM * FFD, b2 + (size_t)l * DIM, h,
            h, NT, DIM, FFD, /*fp32 out*/0);
    }

    hipMemcpyAsync(d_out, h + (size_t)NORI * DIM, (size_t)NG * DIM * sizeof(float),
                   hipMemcpyDeviceToDevice, stream);
}

// Round 4
// 514.984 us; speedup vs baseline: 2.9659x; 1.1922x over previous
//
#include <hip/hip_runtime.h>

// Graphormer encoder — bf16 MFMA GEMMs, fp32 residual path.
// Attention is block-diagonal (64 graphs x 32 nodes) — never materialize [N,N].
// Round 4: BM=64 everywhere + split-K w/ atomicAdd into fp32 residual buffer.

#define NG   64
#define NP   31
#define NORI 1984
#define NT   2048
#define DIM  512
#define NHD  8
#define DKH  64
#define FFD  2048
#define NLAY 4
#define NFEA 32

typedef __attribute__((ext_vector_type(8))) short short8;
typedef __attribute__((ext_vector_type(4))) float floatx4;

__device__ __forceinline__ unsigned short f2bf(float f) {
    union { float f; unsigned u; } v; v.f = f;
    unsigned r = v.u + 0x7fffu + ((v.u >> 16) & 1u);
    return (unsigned short)(r >> 16);
}
__device__ __forceinline__ float bf2f(unsigned short u) {
    union { unsigned u; float f; } v; v.u = ((unsigned)u) << 16;
    return v.f;
}

// ---------------------------------------------------------------- build B blocks
__global__ __launch_bounds__(256) void build_B(
    const int* __restrict__ sp, const float* __restrict__ db,
    const float* __restrict__ virt_bias, float* __restrict__ Bg)
{
    int g = blockIdx.x;
    float vb = virt_bias[0];
    for (int e = threadIdx.x; e < 1024; e += 256) {
        int i = e >> 5, j = e & 31;
        float v;
        if (i == j) v = db[0];
        else if (i < NP && j < NP) {
            int s = sp[(size_t)(g * NP + i) * NORI + g * NP + j];
            v = db[s < 100 ? s : 100];
        } else v = vb;
        Bg[(size_t)g * 1024 + e] = v;
    }
}

// ---------------------------------------------------------------- init h (fp32)
__global__ __launch_bounds__(256) void init_h(
    const float* __restrict__ x, const int* __restrict__ degrees,
    const float* __restrict__ init_W, const float* __restrict__ init_b,
    const float* __restrict__ cent_emb, float* __restrict__ h)
{
    int n = blockIdx.x;
    int tid = threadIdx.x;
    __shared__ float xs[NFEA];
    if (n < NORI && tid < NFEA) xs[tid] = x[(size_t)n * NFEA + tid];
    __syncthreads();
    int deg = degrees[n]; if (deg > 100) deg = 100;
    for (int d = tid; d < DIM; d += 256) {
        float v = cent_emb[(size_t)deg * DIM + d];
        if (n < NORI) {
            float acc = init_b[d];
            #pragma unroll
            for (int k = 0; k < NFEA; ++k) acc += xs[k] * init_W[(size_t)k * DIM + d];
            v += acc;
        }
        h[(size_t)n * DIM + d] = v;
    }
}

// ---------------------------------------------------------------- weight prep
// QKV: Wq/Wk/Wv [L,H,D,DK] -> Wqkv_t [L][1536][512] bf16 (row = which*512+h*64+k, col = d)
__global__ __launch_bounds__(256) void qkv_prep(
    const float* __restrict__ Wq, const float* __restrict__ Wk, const float* __restrict__ Wv,
    unsigned short* __restrict__ Wt)
{
    int tile = blockIdx.x;          // 96 slices * 32 tiles
    int slice = tile >> 5;
    int tloc = tile & 31;
    int dt = tloc >> 1, kt = tloc & 1;
    int l = slice / 24; int rem = slice % 24; int which = rem >> 3; int hh = rem & 7;
    const float* W = (which == 0) ? Wq : (which == 1) ? Wk : Wv;
    const float* in = W + (size_t)(l * 8 + hh) * DIM * DKH;
    __shared__ float tl[32][33];
    int tr = threadIdx.x >> 5, tc = threadIdx.x & 31;
    #pragma unroll
    for (int p = 0; p < 4; ++p)
        tl[tr + p * 8][tc] = in[(size_t)(dt * 32 + tr + p * 8) * DKH + kt * 32 + tc];
    __syncthreads();
    unsigned short* out = Wt + ((size_t)l * 1536 + which * 512 + hh * 64 + kt * 32) * DIM + dt * 32;
    #pragma unroll
    for (int p = 0; p < 4; ++p)
        out[(size_t)(tr + p * 8) * DIM + tc] = f2bf(tl[tc][tr + p * 8]);
}

__global__ __launch_bounds__(256) void bias_prep(
    const float* __restrict__ bq, const float* __restrict__ bk, const float* __restrict__ bv,
    float* __restrict__ bqkv)
{
    int idx = blockIdx.x * 256 + threadIdx.x;
    if (idx >= NLAY * 1536) return;
    int l = idx / 1536, c = idx % 1536;
    int which = c >> 9, cc = c & 511;
    const float* b = (which == 0) ? bq : (which == 1) ? bk : bv;
    bqkv[idx] = b[(size_t)l * 512 + cc];
}

// generic per-layer transpose: in [L][R][C] fp32 -> out [L][C][R] bf16
__global__ __launch_bounds__(256) void transpose_bf16(
    const float* __restrict__ in, unsigned short* __restrict__ out, int R, int C)
{
    int l = blockIdx.z;
    const float* ip = in + (size_t)l * R * C;
    unsigned short* op = out + (size_t)l * R * C;
    int r0 = blockIdx.y * 32, c0 = blockIdx.x * 32;
    __shared__ float tl[32][33];
    int tr = threadIdx.x >> 5, tc = threadIdx.x & 31;
    #pragma unroll
    for (int p = 0; p < 4; ++p)
        tl[tr + p * 8][tc] = ip[(size_t)(r0 + tr + p * 8) * C + c0 + tc];
    __syncthreads();
    #pragma unroll
    for (int p = 0; p < 4; ++p)
        op[(size_t)(c0 + tr + p * 8) * R + r0 + tc] = f2bf(tl[tc][tr + p * 8]);
}

// ---------------------------------------------------------------- layernorm: fp32 in -> bf16 out
__global__ __launch_bounds__(256) void layernorm_bf16(
    const float* __restrict__ in, unsigned short* __restrict__ out)
{
    int n = blockIdx.x;
    int tid = threadIdx.x;
    const float* row = in + (size_t)n * DIM;
    float v0 = row[tid], v1 = row[tid + 256];
    float s = v0 + v1;
    float sq = v0 * v0 + v1 * v1;
    #pragma unroll
    for (int off = 32; off > 0; off >>= 1) {
        s  += __shfl_down(s, off);
        sq += __shfl_down(sq, off);
    }
    __shared__ float red[8];
    int wave = tid >> 6;
    if ((tid & 63) == 0) { red[wave] = s; red[4 + wave] = sq; }
    __syncthreads();
    float ts  = red[0] + red[1] + red[2] + red[3];
    float tsq = red[4] + red[5] + red[6] + red[7];
    float m   = ts * (1.0f / DIM);
    float var = tsq * (1.0f / DIM) - m * m;
    float inv = rsqrtf(var + 1e-5f);
    out[(size_t)n * DIM + tid]       = f2bf((v0 - m) * inv);
    out[(size_t)n * DIM + tid + 256] = f2bf((v1 - m) * inv);
}

// ---------------------------------------------------------------- bf16 MFMA GEMM
// C[M,N] = A[M,K] @ Bt[N,K]^T. Tile 64x64x64, 256 thr, wave = 32x32 (2x2 frags).
// SPLITK==1: out = +bias (+relu) (+resid), fp32 or bf16 per flags.
// SPLITK>1:  out is fp32 accumulator (already holding residual); each kz slice
//            atomicAdds its partial; kz==0 also adds bias. flags ignored.
// flags: 1 = relu, 2 = bf16 output
template<int SPLITK>
__global__ __launch_bounds__(256) void gemm_bf16(
    const unsigned short* __restrict__ A, const unsigned short* __restrict__ Bt,
    const float* __restrict__ bias, const float* __restrict__ resid,
    void* __restrict__ out, int M, int N, int K, int flags)
{
    __shared__ __align__(16) unsigned short Asl[64 * 72];
    __shared__ __align__(16) unsigned short Bsl[64 * 72];
    int tid = threadIdx.x;
    int row0 = blockIdx.y * 64, col0 = blockIdx.x * 64;
    int kslice = K / SPLITK;
    int kbeg = blockIdx.z * kslice;
    int wave = tid >> 6, lane = tid & 63;
    int quad = lane >> 4, m16 = lane & 15;
    int mw = (wave >> 1) * 32, nw = (wave & 1) * 32;
    floatx4 acc[2][2] = {};
    for (int k0 = kbeg; k0 < kbeg + kslice; k0 += 64) {
        #pragma unroll
        for (int p = 0; p < 2; ++p) {
            int idx = (p * 256 + tid) * 8;
            int r = idx >> 6, kk = idx & 63;
            *(float4*)(Asl + r * 72 + kk) =
                *(const float4*)(A + (size_t)(row0 + r) * K + k0 + kk);
            *(float4*)(Bsl + r * 72 + kk) =
                *(const float4*)(Bt + (size_t)(col0 + r) * K + k0 + kk);
        }
        __syncthreads();
        #pragma unroll
        for (int ks = 0; ks < 64; ks += 32) {
            short8 a[2], b[2];
            #pragma unroll
            for (int mi = 0; mi < 2; ++mi)
                a[mi] = *(const short8*)(Asl + (mw + mi * 16 + m16) * 72 + ks + quad * 8);
            #pragma unroll
            for (int ni = 0; ni < 2; ++ni)
                b[ni] = *(const short8*)(Bsl + (nw + ni * 16 + m16) * 72 + ks + quad * 8);
            #pragma unroll
            for (int mi = 0; mi < 2; ++mi)
                #pragma unroll
                for (int ni = 0; ni < 2; ++ni)
                    acc[mi][ni] = __builtin_amdgcn_mfma_f32_16x16x32_bf16(
                        a[mi], b[ni], acc[mi][ni], 0, 0, 0);
        }
        __syncthreads();
    }
    if (SPLITK == 1) {
        int do_relu = flags & 1, out_bf = flags & 2;
        #pragma unroll
        for (int mi = 0; mi < 2; ++mi) {
            #pragma unroll
            for (int ni = 0; ni < 2; ++ni) {
                int col = col0 + nw + ni * 16 + m16;
                float bval = bias ? bias[col] : 0.0f;
                #pragma unroll
                for (int rr = 0; rr < 4; ++rr) {
                    int row = row0 + mw + mi * 16 + quad * 4 + rr;
                    float v = acc[mi][ni][rr] + bval;
                    if (do_relu) v = fmaxf(v, 0.0f);
                    if (resid) v += resid[(size_t)row * N + col];
                    if (out_bf) ((unsigned short*)out)[(size_t)row * N + col] = f2bf(v);
                    else        ((float*)out)[(size_t)row * N + col] = v;
                }
            }
        }
    } else {
        float* o = (float*)out;
        float bscale = (blockIdx.z == 0) ? 1.0f : 0.0f;
        #pragma unroll
        for (int mi = 0; mi < 2; ++mi) {
            #pragma unroll
            for (int ni = 0; ni < 2; ++ni) {
                int col = col0 + nw + ni * 16 + m16;
                float bval = bias[col] * bscale;
                #pragma unroll
                for (int rr = 0; rr < 4; ++rr) {
                    int row = row0 + mw + mi * 16 + quad * 4 + rr;
                    atomicAdd(&o[(size_t)row * N + col], acc[mi][ni][rr] + bval);
                }
            }
        }
    }
}

// ---------------------------------------------------------------- block attention (bf16 io)
// Padded LDS strides (65 / 33) -> conflict-free: Ks bank = (sj+k)%32 over sj.
__global__ __launch_bounds__(256) void attention(
    const unsigned short* __restrict__ qkv,  // [NT][1536] bf16, Q|K|V head-major
    const float* __restrict__ Bg,            // [NG][32][32]
    unsigned short* __restrict__ O)          // [NT][512] bf16 head-major
{
    int g = blockIdx.x >> 3;
    int hh = blockIdx.x & 7;
    __shared__ float Qs[32][65], Ks[32][65], Vs[32][65];
    __shared__ float S[32][33];
    int tid = threadIdx.x;
    int i = tid >> 3;
    int c0 = (tid & 7) * 8;
    int gn = (i < NP) ? g * NP + i : NORI + g;
    const unsigned short* base = qkv + (size_t)gn * 1536 + hh * DKH;
    short8 qv = *(const short8*)(base + c0);
    short8 kv = *(const short8*)(base + 512 + c0);
    short8 vv = *(const short8*)(base + 1024 + c0);
    #pragma unroll
    for (int j = 0; j < 8; ++j) {
        Qs[i][c0 + j] = bf2f((unsigned short)qv[j]);
        Ks[i][c0 + j] = bf2f((unsigned short)kv[j]);
        Vs[i][c0 + j] = bf2f((unsigned short)vv[j]);
    }
    __syncthreads();
    const float scale = 0.125f;  // 1/sqrt(64)
    #pragma unroll
    for (int e = 0; e < 4; ++e) {
        int idx = tid + e * 256;
        int si = idx >> 5, sj = idx & 31;
        float dot = 0.0f;
        #pragma unroll
        for (int k = 0; k < DKH; ++k) dot += Qs[si][k] * Ks[sj][k];
        S[si][sj] = dot * scale + Bg[(size_t)g * 1024 + si * 32 + sj];
    }
    __syncthreads();
    if (tid < 32) {
        float mx = -1e30f;
        #pragma unroll
        for (int j = 0; j < 32; ++j) mx = fmaxf(mx, S[tid][j]);
        float sum = 0.0f;
        #pragma unroll
        for (int j = 0; j < 32; ++j) { float e = __expf(S[tid][j] - mx); S[tid][j] = e; sum += e; }
        float inv = 1.0f / sum;
        #pragma unroll
        for (int j = 0; j < 32; ++j) S[tid][j] *= inv;
    }
    __syncthreads();
    short8 ov;
    #pragma unroll
    for (int cc = 0; cc < 8; ++cc) {
        float acc = 0.0f;
        #pragma unroll
        for (int j = 0; j < 32; ++j) acc += S[i][j] * Vs[j][c0 + cc];
        ov[cc] = (short)f2bf(acc);
    }
    *(short8*)(O + (size_t)gn * DIM + hh * DKH + c0) = ov;
}

// ---------------------------------------------------------------- launch
extern "C" void kernel_launch(void* const* d_in, const int* in_sizes, int n_in,
                              void* d_out, int out_size, void* d_ws, size_t ws_size,
                              hipStream_t stream)
{
    const float* x        = (const float*)d_in[0];
    const int*   sp       = (const int*)d_in[1];
    const int*   degrees  = (const int*)d_in[3];
    const float* init_W   = (const float*)d_in[4];
    const float* init_b   = (const float*)d_in[5];
    const float* cent_emb = (const float*)d_in[6];
    const float* db       = (const float*)d_in[7];
    const float* vbias    = (const float*)d_in[8];
    const float* Wq       = (const float*)d_in[9];
    const float* bq       = (const float*)d_in[10];
    const float* Wk       = (const float*)d_in[11];
    const float* bk       = (const float*)d_in[12];
    const float* Wv       = (const float*)d_in[13];
    const float* bv       = (const float*)d_in[14];
    const float* Wo       = (const float*)d_in[15];
    const float* bo       = (const float*)d_in[16];
    const float* W1       = (const float*)d_in[17];
    const float* b1       = (const float*)d_in[18];
    const float* W2       = (const float*)d_in[19];
    const float* b2       = (const float*)d_in[20];

    char* ws = (char*)d_ws;
    float*          h      = (float*)ws;          ws += (size_t)NT * DIM * 4;       // 4 MB
    unsigned short* hn     = (unsigned short*)ws; ws += (size_t)NT * DIM * 2;       // 2 MB
    unsigned short* o      = (unsigned short*)ws; ws += (size_t)NT * DIM * 2;       // 2 MB
    unsigned short* qkv    = (unsigned short*)ws; ws += (size_t)NT * FFD * 2;       // 8 MB (aliased: qkv / ffn)
    float*          Bg     = (float*)ws;          ws += (size_t)NG * 1024 * 4;      // 256 KB
    unsigned short* Wqkv_t = (unsigned short*)ws; ws += (size_t)NLAY * 1536 * DIM * 2; // 6 MB
    unsigned short* Wo_t   = (unsigned short*)ws; ws += (size_t)NLAY * DIM * DIM * 2;  // 2 MB
    unsigned short* W1_t   = (unsigned short*)ws; ws += (size_t)NLAY * FFD * DIM * 2;  // 8 MB
    unsigned short* W2_t   = (unsigned short*)ws; ws += (size_t)NLAY * DIM * FFD * 2;  // 8 MB
    float*          bqkv   = (float*)ws;          ws += (size_t)NLAY * 1536 * 4;
    unsigned short* ffnb   = qkv;  // alias: qkv dead after attention, ffnb dead after GEMM4

    // prep
    build_B<<<NG, 256, 0, stream>>>(sp, db, vbias, Bg);
    init_h<<<NT, 256, 0, stream>>>(x, degrees, init_W, init_b, cent_emb, h);
    qkv_prep<<<96 * 32, 256, 0, stream>>>(Wq, Wk, Wv, Wqkv_t);
    bias_prep<<<(NLAY * 1536 + 255) / 256, 256, 0, stream>>>(bq, bk, bv, bqkv);
    transpose_bf16<<<dim3(DIM / 32, DIM / 32, NLAY), 256, 0, stream>>>(Wo, Wo_t, DIM, DIM);
    transpose_bf16<<<dim3(FFD / 32, DIM / 32, NLAY), 256, 0, stream>>>(W1, W1_t, DIM, FFD);
    transpose_bf16<<<dim3(DIM / 32, FFD / 32, NLAY), 256, 0, stream>>>(W2, W2_t, FFD, DIM);

    for (int l = 0; l < NLAY; ++l) {
        layernorm_bf16<<<NT, 256, 0, stream>>>(h, hn);
        gemm_bf16<1><<<dim3(1536 / 64, NT / 64), 256, 0, stream>>>(
            hn, Wqkv_t + (size_t)l * 1536 * DIM, bqkv + (size_t)l * 1536, nullptr,
            qkv, NT, 1536, DIM, /*bf16 out*/2);
        attention<<<NG * NHD, 256, 0, stream>>>(qkv, Bg, o);
        // h += o @ Wo^T + bo   (split-K=2, atomic accumulate into h)
        gemm_bf16<2><<<dim3(DIM / 64, NT / 64, 2), 256, 0, stream>>>(
            o, Wo_t + (size_t)l * DIM * DIM, bo + (size_t)l * DIM, nullptr,
            h, NT, DIM, DIM, 0);
        layernorm_bf16<<<NT, 256, 0, stream>>>(h, hn);
        gemm_bf16<1><<<dim3(FFD / 64, NT / 64), 256, 0, stream>>>(
            hn, W1_t + (size_t)l * FFD * DIM, b1 + (size_t)l * FFD, nullptr,
            ffnb, NT, FFD, DIM, /*relu + bf16 out*/3);
        // h += relu(...) @ W2^T + b2   (split-K=4, atomic accumulate into h)
        gemm_bf16<4><<<dim3(DIM / 64, NT / 64, 4), 256, 0, stream>>>(
            ffnb, W2_t + (size_t)l * DIM * FFD, b2 + (size_t)l * DIM, nullptr,
            h, NT, DIM, FFD, 0);
    }

    hipMemcpyAsync(d_out, h + (size_t)NORI * DIM, (size_t)NG * DIM * sizeof(float),
                   hipMemcpyDeviceToDevice, stream);
}